// Round 1
// baseline (334.014 us; speedup 1.0000x reference)
//
#include <hip/hip_runtime.h>

typedef __attribute__((ext_vector_type(8))) short short8;
typedef __attribute__((ext_vector_type(4))) short short4_t;
typedef __attribute__((ext_vector_type(4))) float float4_t;
typedef __attribute__((ext_vector_type(16))) float float16_t;

#define NTOK 4096
#define CDIM 256
#define BPB (NTOK * CDIM)
#define C1 0.0901684400555602f   /* log2(e) / sqrt(256) */

__device__ inline float bf2f(short s) {
    return __uint_as_float(((unsigned)(unsigned short)s) << 16);
}
__device__ inline short f2bf(float f) {
    unsigned u = __float_as_uint(f);
    return (short)((u + 0x7fffu + ((u >> 16) & 1u)) >> 16);
}
// direct global->LDS DMA, 16B per lane, dest must be lane-linear
__device__ inline void gl_lds16(const void* g, void* l) {
    __builtin_amdgcn_global_load_lds(
        (const __attribute__((address_space(1))) unsigned int*)g,
        (__attribute__((address_space(3))) unsigned int*)l, 16, 0, 0);
}

// ---------------------------------------------------------------------------
__global__ void sniff_dtype(const unsigned* __restrict__ x, int* __restrict__ flag) {
    __shared__ int cnt;
    if (threadIdx.x == 0) cnt = 0;
    __syncthreads();
    int local = 0;
    for (int i = threadIdx.x; i < 1024; i += 256) {
        unsigned e = (x[i] >> 7) & 0xffu;
        if (e >= 100u && e <= 140u) local++;
    }
    atomicAdd(&cnt, local);
    __syncthreads();
    if (threadIdx.x == 0) flag[0] = (cnt >= 512) ? 1 : 0;
}

// ---------------------------------------------------------------------------
// wprep: convert Wq|Wk|Wv to bf16 into workspace (once; 768 KB read).
// ---------------------------------------------------------------------------
__global__ __launch_bounds__(256) void wprep(
    const void* __restrict__ Wq, const void* __restrict__ Wk,
    const void* __restrict__ Wv, const int* __restrict__ flag,
    short* __restrict__ Wb)
{
    const int base = (blockIdx.x * 256 + threadIdx.x) * 8;   // [0, 196608)
    const int wsel = base >> 16, off = base & 65535;
    const void* W = (wsel == 0) ? Wq : (wsel == 1) ? Wk : Wv;
    short8 v;
    if (flag[0]) {
        v = *(const short8*)((const short*)W + off);
    } else {
        const float* f = (const float*)W + off;
        float4 a = *(const float4*)f;
        float4 c4 = *(const float4*)(f + 4);
        v[0]=f2bf(a.x);  v[1]=f2bf(a.y);  v[2]=f2bf(a.z);  v[3]=f2bf(a.w);
        v[4]=f2bf(c4.x); v[5]=f2bf(c4.y); v[6]=f2bf(c4.z); v[7]=f2bf(c4.w);
    }
    *(short8*)(Wb + base) = v;
}

// ---------------------------------------------------------------------------
// qkv5: fused transpose + QKV projection.  One block = 64 tokens x all 3 W.
// X tile transposed through LDS (one barrier total); W(bf16, prepped) frags
// loaded DIRECTLY from global (L1/L2-hot: all 4 waves read the same rows).
// Q,K stored [n][d]; V stored transposed AND bank-swizzled: VT[d][tile*64 +
// ((g ^ (d&7))*8 + j)] so flash10 can global_load_lds it linearly.
// ---------------------------------------------------------------------------
template <bool PIN>
__global__ __launch_bounds__(256, 2) void qkv5(
    const void* __restrict__ xv, const short* __restrict__ Wb,
    const void* __restrict__ bq, const void* __restrict__ bk,
    const void* __restrict__ bv,
    const int* __restrict__ flag, int b0,
    short* __restrict__ qbase, short* __restrict__ kbase,
    short* __restrict__ vtbase)
{
    int nt, bl;
    if (PIN) {
        bl = (blockIdx.x >> 1) & 3;
        nt = ((blockIdx.x >> 3) << 1) | (blockIdx.x & 1);
    } else { nt = blockIdx.x; bl = blockIdx.z; }
    const int b = b0 + bl;
    const int n0 = nt * 64;
    const int tid = threadIdx.x;
    const int w = tid >> 6, lane = tid & 63, l15 = lane & 15, qd = lane >> 4;
    const int isbf = flag[0];

    __shared__ short xt[64 * 264];     // 33792 B (only LDS use)

    // ---- stage X tile transposed: thread owns channel c = tid ----
    {
        const size_t xb = (size_t)b * CDIM * NTOK + (size_t)tid * NTOK + n0;
        if (isbf) {
            const short* x = (const short*)xv;
            #pragma unroll
            for (int i = 0; i < 8; ++i) {
                short8 v = *(const short8*)(x + xb + i * 8);
                #pragma unroll
                for (int j = 0; j < 8; ++j) xt[(i * 8 + j) * 264 + tid] = v[j];
            }
        } else {
            const float* x = (const float*)xv;
            #pragma unroll
            for (int i = 0; i < 16; ++i) {
                float4 v = *(const float4*)(x + xb + i * 4);
                xt[(i * 4 + 0) * 264 + tid] = f2bf(v.x);
                xt[(i * 4 + 1) * 264 + tid] = f2bf(v.y);
                xt[(i * 4 + 2) * 264 + tid] = f2bf(v.z);
                xt[(i * 4 + 3) * 264 + tid] = f2bf(v.w);
            }
        }
    }
    __syncthreads();   // the only barrier

    short8 af[8];
    #pragma unroll
    for (int s = 0; s < 8; ++s)
        af[s] = *(const short8*)&xt[(16 * w + l15) * 264 + s * 32 + qd * 8];

    short* qdst  = qbase  + (size_t)bl * BPB;
    short* kdst  = kbase  + (size_t)bl * BPB;
    short* vtdst = vtbase + (size_t)bl * BPB;

    #pragma unroll 1
    for (int wsel = 0; wsel < 3; ++wsel) {
        const short* W = Wb + wsel * 65536;
        const void* bp = (wsel == 0) ? bq : (wsel == 1) ? bk : bv;
        #pragma unroll 1
        for (int dh = 0; dh < 4; ++dh) {
            #pragma unroll
            for (int dt = 0; dt < 4; ++dt) {
                const int d = dh * 64 + dt * 16 + l15;
                const short* wr = W + (size_t)d * 256 + qd * 8;
                float4_t acc = {0.f, 0.f, 0.f, 0.f};
                #pragma unroll
                for (int s = 0; s < 8; ++s) {
                    short8 wb = *(const short8*)(wr + s * 32);
                    acc = __builtin_amdgcn_mfma_f32_16x16x32_bf16(af[s], wb, acc, 0, 0, 0);
                }
                const float bias = isbf ? bf2f(((const short*)bp)[d])
                                        : ((const float*)bp)[d];
                if (wsel < 2) {
                    short* dst = (wsel == 0) ? qdst : kdst;
                    #pragma unroll
                    for (int r = 0; r < 4; ++r) {
                        const int n = n0 + 16 * w + 4 * qd + r;
                        dst[(size_t)n * 256 + d] = f2bf(acc[r] + bias);
                    }
                } else {
                    short4_t pk;
                    #pragma unroll
                    for (int r = 0; r < 4; ++r) pk[r] = f2bf(acc[r] + bias);
                    const int nb4 = 16 * w + 4 * qd;
                    const int col = (((nb4 >> 3) ^ (d & 7)) << 3) | (nb4 & 7);
                    *(short4_t*)(vtdst + (size_t)d * NTOK + n0 + col) = pk;
                }
            }
        }
    }
}

// ---------------------------------------------------------------------------
// flash10: 32x32x16 MFMA flash attention, ONE barrier per K-tile.
//  - K fragments loaded DIRECTLY from global into regs, prefetched one iter
//    ahead (the barrier's vmcnt(0) drain completes them for free).
//  - V staged via global_load_lds from pre-swizzled VT (no reg roundtrip,
//    no ds_writes); issued at iter kt, consumed at iter kt+1.
//  - LDS = 80 KB -> 2 blocks/CU when grid > 256.
//  - SPLIT: grid 512, each block does half the key range, writes f32
//    unnormalized O-partials + l-partials; combine() normalizes.
// ---------------------------------------------------------------------------
template <bool PIN, bool SPLIT>
__global__ __launch_bounds__(256, 2) void flash10(
    int b0, const short* __restrict__ qb, const short* __restrict__ kb,
    const short* __restrict__ vts, const int* __restrict__ flag,
    void* __restrict__ outv, float* __restrict__ pO, float* __restrict__ pl)
{
    int qt, bl, half;
    if (SPLIT) {
        bl = (blockIdx.x >> 1) & 3;
        const int id = ((blockIdx.x >> 3) << 1) | (blockIdx.x & 1);
        qt = id >> 1; half = id & 1;
    } else if (PIN) {
        bl = (blockIdx.x >> 1) & 3;
        qt = ((blockIdx.x >> 3) << 1) | (blockIdx.x & 1);
        half = 0;
    } else { qt = blockIdx.x; bl = blockIdx.z; half = 0; }

    const int b = b0 + bl;
    const int q0 = qt * 64;
    const int tid = threadIdx.x;
    const int w = tid >> 6, lane = tid & 63, l31 = lane & 31, h = lane >> 5;
    const int wi = w & 1, wh = w >> 1;
    const int KT0 = SPLIT ? (half << 5) : 0;
    const int KT1 = KT0 + (SPLIT ? 32 : 64);

    __shared__ char smem[81920];
    short* vbufA = (short*)smem;               // 2 x 32 KB
    short* pbufA = (short*)(smem + 65536);     // 2 x 8 KB

    const short* Q  = qb  + (size_t)bl * BPB;
    const short* K  = kb  + (size_t)bl * BPB;
    const short* VT = vts + (size_t)bl * BPB;

    // Q B-frags: lane n=l31 -> row q0+32wh+l31, k = 8h+j
    short8 qf[16];
    {
        const short* qrow = Q + (size_t)(q0 + 32 * wh + l31) * 256 + h * 8;
        #pragma unroll
        for (int s = 0; s < 16; ++s)
            qf[s] = *(const short8*)(qrow + s * 16);
    }

    float16_t oacc[4];
    #pragma unroll
    for (int dt = 0; dt < 4; ++dt)
        #pragma unroll
        for (int r = 0; r < 16; ++r) oacc[dt][r] = 0.f;
    float lloc = 0.f;

    const int prow = 32 * wh + l31;
    const short* kr0   = K + (size_t)(32 * wi + l31) * 256 + h * 8;
    const short* vsrc0 = VT + (size_t)(tid >> 3) * NTOK + (tid & 7) * 8;

    // K(KT0) frags directly into regs
    short8 kf[16];
    {
        const short* kr = kr0 + (size_t)KT0 * 16384;
        #pragma unroll
        for (int j = 0; j < 8; ++j) {
            kf[2 * j]     = *(const short8*)(kr + j * 32);
            kf[2 * j + 1] = *(const short8*)(kr + j * 32 + 16);
        }
    }

    #pragma unroll 1
    for (int kt = KT0; kt < KT1; ++kt) {
        short* vcur  = vbufA + (kt & 1) * 16384;
        short* vprev = vbufA + ((kt + 1) & 1) * 16384;
        short* pcur  = pbufA + (kt & 1) * 4096;
        short* pprev = pbufA + ((kt + 1) & 1) * 4096;

        // ---- issue V(kt) DMA -> vcur (consumed next iter; barrier drains) ----
        {
            const short* vs = vsrc0 + kt * 64;
            short* vd = vcur + tid * 8;
            #pragma unroll
            for (int u = 0; u < 8; ++u)
                gl_lds16(vs + (size_t)u * (32 * NTOK), vd + u * 2048);
        }

        // ---- S(kt): pure register MFMA (kf drained by previous barrier) ----
        float16_t se, so;
        #pragma unroll
        for (int r = 0; r < 16; ++r) { se[r] = 0.f; so[r] = 0.f; }
        #pragma unroll
        for (int j = 0; j < 8; ++j) {
            se = __builtin_amdgcn_mfma_f32_32x32x16_bf16(kf[2 * j],     qf[2 * j],     se, 0, 0, 0);
            so = __builtin_amdgcn_mfma_f32_32x32x16_bf16(kf[2 * j + 1], qf[2 * j + 1], so, 0, 0, 0);
        }

        // ---- P = exp2(C1*S); l accumulate; pack to pcur ----
        #pragma unroll
        for (int g2 = 0; g2 < 4; ++g2) {
            short4_t pk;
            #pragma unroll
            for (int r = 0; r < 4; ++r) {
                const float pv = exp2f((se[4 * g2 + r] + so[4 * g2 + r]) * C1);
                lloc += pv;
                pk[r] = f2bf(pv);
            }
            const int gk = 4 * wi + g2;
            *(short4_t*)&pcur[prow * 64 + ((gk ^ (prow & 7)) * 8) + h * 4] = pk;
        }

        // ---- PV(kt-1) ----
        if (kt > KT0) {
            short8 pa[4];
            #pragma unroll
            for (int s2 = 0; s2 < 4; ++s2)
                pa[s2] = *(const short8*)
                    &pprev[prow * 64 + (((2 * s2 + h) ^ (prow & 7)) * 8)];
            #pragma unroll
            for (int dt = 0; dt < 4; ++dt) {
                const int vr = 128 * wi + 32 * dt + l31;
                #pragma unroll
                for (int s2 = 0; s2 < 4; ++s2) {
                    short8 vf = *(const short8*)
                        &vprev[vr * 64 + (((2 * s2 + h) ^ (vr & 7)) * 8)];
                    oacc[dt] = __builtin_amdgcn_mfma_f32_32x32x16_bf16(pa[s2], vf, oacc[dt], 0, 0, 0);
                }
            }
        }

        // ---- K(kt+1) reg prefetch; the barrier drain completes it ----
        if (kt + 1 < KT1) {
            const short* kr = kr0 + (size_t)(kt + 1) * 16384;
            #pragma unroll
            for (int j = 0; j < 8; ++j) {
                kf[2 * j]     = *(const short8*)(kr + j * 32);
                kf[2 * j + 1] = *(const short8*)(kr + j * 32 + 16);
            }
        }

        __syncthreads();   // the ONE barrier
    }

    // ---- drain: PV(KT1-1) (KT1-1 is odd in all modes -> buffers at +1) ----
    {
        short* pprev = pbufA + 4096;
        short* vprev = vbufA + 16384;
        short8 pa[4];
        #pragma unroll
        for (int s2 = 0; s2 < 4; ++s2)
            pa[s2] = *(const short8*)
                &pprev[prow * 64 + (((2 * s2 + h) ^ (prow & 7)) * 8)];
        #pragma unroll
        for (int dt = 0; dt < 4; ++dt) {
            const int vr = 128 * wi + 32 * dt + l31;
            #pragma unroll
            for (int s2 = 0; s2 < 4; ++s2) {
                short8 vf = *(const short8*)
                    &vprev[vr * 64 + (((2 * s2 + h) ^ (vr & 7)) * 8)];
                oacc[dt] = __builtin_amdgcn_mfma_f32_32x32x16_bf16(pa[s2], vf, oacc[dt], 0, 0, 0);
            }
        }
    }
    __syncthreads();   // all LDS reads done before epilogue overlays

    if (SPLIT) {
        float* lbuf = (float*)smem;
        {
            float v2 = lloc + __shfl_xor(lloc, 32, 64);
            if (h == 0) lbuf[(32 * wh + l31) * 2 + wi] = v2;
        }
        const size_t pidx = (size_t)(bl * 64 + qt) * 2 + half;
        float* po = pO + pidx * 16384;
        #pragma unroll
        for (int dt = 0; dt < 4; ++dt) {
            const int dim = 128 * wi + 32 * dt + l31;
            #pragma unroll
            for (int r = 0; r < 16; ++r) {
                const int qrow = 32 * wh + (r & 3) + 8 * (r >> 2) + 4 * h;
                po[qrow * 256 + dim] = oacc[dt][r];
            }
        }
        __syncthreads();
        if (tid < 64) pl[pidx * 64 + tid] = lbuf[2 * tid] + lbuf[2 * tid + 1];
    } else {
        float* obuf = (float*)smem;               // 64 x 260 fp32
        float* lbuf = (float*)(smem + 66560);     // 64 x 2 fp32
        {
            float v2 = lloc + __shfl_xor(lloc, 32, 64);
            if (h == 0) lbuf[(32 * wh + l31) * 2 + wi] = v2;
        }
        #pragma unroll
        for (int dt = 0; dt < 4; ++dt) {
            const int dim = 128 * wi + 32 * dt + l31;
            #pragma unroll
            for (int r = 0; r < 16; ++r) {
                const int qrow = 32 * wh + (r & 3) + 8 * (r >> 2) + 4 * h;
                obuf[qrow * 260 + dim] = oacc[dt][r];
            }
        }
        __syncthreads();
        {
            const int row = tid >> 2, q4 = (tid & 3) * 64;
            const float inv = 1.0f / (lbuf[2 * row] + lbuf[2 * row + 1]);
            const float* src = obuf + row * 260 + q4;
            const size_t o = (size_t)(b * NTOK + q0 + row) * 256 + q4;
            if (flag[0]) {
                short* op = (short*)outv;
                #pragma unroll
                for (int g = 0; g < 4; ++g) {
                    float4 a  = *(const float4*)(src + g * 8);
                    float4 c4 = *(const float4*)(src + g * 8 + 4);
                    short8 pk;
                    pk[0]=f2bf(a.x*inv);  pk[1]=f2bf(a.y*inv);
                    pk[2]=f2bf(a.z*inv);  pk[3]=f2bf(a.w*inv);
                    pk[4]=f2bf(c4.x*inv); pk[5]=f2bf(c4.y*inv);
                    pk[6]=f2bf(c4.z*inv); pk[7]=f2bf(c4.w*inv);
                    *(short8*)(op + o + g * 8) = pk;
                }
            } else {
                float* op = (float*)outv;
                #pragma unroll
                for (int g = 0; g < 16; ++g) {
                    float4 a = *(const float4*)(src + g * 4);
                    a.x *= inv; a.y *= inv; a.z *= inv; a.w *= inv;
                    *(float4*)(op + o + g * 4) = a;
                }
            }
        }
    }
}

// ---------------------------------------------------------------------------
// combine: out[n][d] = (Oa+Ob) / (la+lb), cast per flag.  Grid 256 (tiles).
// ---------------------------------------------------------------------------
__global__ __launch_bounds__(256) void combine(
    const float* __restrict__ pO, const float* __restrict__ pl,
    const int* __restrict__ flag, void* __restrict__ outv)
{
    const int tile = blockIdx.x, tid = threadIdx.x;
    const int row = tid >> 2, seg = (tid & 3) * 64;
    const float* A = pO + (size_t)tile * 32768 + row * 256 + seg;
    const float* B = A + 16384;
    const float inv = 1.0f / (pl[tile * 128 + row] + pl[tile * 128 + 64 + row]);
    const size_t o = ((size_t)tile * 64 + row) * 256 + seg;
    if (flag[0]) {
        short* op = (short*)outv;
        #pragma unroll
        for (int g = 0; g < 8; ++g) {
            float4 a  = *(const float4*)(A + g * 8);
            float4 a2 = *(const float4*)(A + g * 8 + 4);
            float4 c  = *(const float4*)(B + g * 8);
            float4 c2 = *(const float4*)(B + g * 8 + 4);
            short8 pk;
            pk[0]=f2bf((a.x+c.x)*inv);   pk[1]=f2bf((a.y+c.y)*inv);
            pk[2]=f2bf((a.z+c.z)*inv);   pk[3]=f2bf((a.w+c.w)*inv);
            pk[4]=f2bf((a2.x+c2.x)*inv); pk[5]=f2bf((a2.y+c2.y)*inv);
            pk[6]=f2bf((a2.z+c2.z)*inv); pk[7]=f2bf((a2.w+c2.w)*inv);
            *(short8*)(op + o + g * 8) = pk;
        }
    } else {
        float* op = (float*)outv;
        #pragma unroll
        for (int g = 0; g < 16; ++g) {
            float4 a = *(const float4*)(A + g * 4);
            float4 c = *(const float4*)(B + g * 4);
            a.x = (a.x + c.x) * inv; a.y = (a.y + c.y) * inv;
            a.z = (a.z + c.z) * inv; a.w = (a.w + c.w) * inv;
            *(float4*)(op + o + g * 4) = a;
        }
    }
}

extern "C" void kernel_launch(void* const* d_in, const int* in_sizes, int n_in,
                              void* d_out, int out_size, void* d_ws, size_t ws_size,
                              hipStream_t stream)
{
    const size_t HDR = 256;
    const size_t WBB = 393216;                     // 3 x 256 x 256 bf16
    const size_t TB  = (size_t)BPB * 2;            // 2 MB per batch per tensor
    const size_t OFF_K = HDR + WBB;
    const size_t need_prim  = OFF_K + 12 * TB;             // + K|VT|Q (24 MB)
    const size_t need_split = need_prim + 33554432 + 131072; // + partials

    int*   flag = (int*)d_ws;
    short* Wb   = (short*)((char*)d_ws + HDR);

    sniff_dtype<<<1, 256, 0, stream>>>((const unsigned*)d_in[0], flag);
    wprep<<<96, 256, 0, stream>>>(d_in[1], d_in[3], d_in[5], flag, Wb);

    if (ws_size >= need_prim) {
        short* kbase  = (short*)((char*)d_ws + OFF_K);
        short* vtbase = kbase  + 4 * (size_t)BPB;
        short* qbase  = vtbase + 4 * (size_t)BPB;
        qkv5<true><<<dim3(256, 1, 1), 256, 0, stream>>>(
            d_in[0], Wb, d_in[2], d_in[4], d_in[6], flag, 0,
            qbase, kbase, vtbase);
        if (ws_size >= need_split) {
            float* pO = (float*)((char*)d_ws + need_prim);
            float* pl = (float*)((char*)d_ws + need_prim + 33554432);
            flash10<true, true><<<dim3(512, 1, 1), 256, 0, stream>>>(
                0, qbase, kbase, vtbase, flag, d_out, pO, pl);
            combine<<<dim3(256, 1, 1), 256, 0, stream>>>(pO, pl, flag, d_out);
        } else {
            flash10<true, false><<<dim3(256, 1, 1), 256, 0, stream>>>(
                0, qbase, kbase, vtbase, flag, d_out, nullptr, nullptr);
        }
        return;
    }

    // fallback: batch-chunked (K|VT|Q per chunk = 6 MB/batch)
    int nb = 4;
    while (nb > 1 && ws_size < OFF_K + (size_t)nb * 3 * TB) nb--;
    short* kbase  = (short*)((char*)d_ws + OFF_K);
    short* vtbase = kbase + (size_t)nb * BPB;
    short* qbase  = vtbase + (size_t)nb * BPB;

    for (int b0 = 0; b0 < 4; b0 += nb) {
        const int nbc = (4 - b0) < nb ? (4 - b0) : nb;
        qkv5<false><<<dim3(64, 1, nbc), 256, 0, stream>>>(
            d_in[0], Wb, d_in[2], d_in[4], d_in[6], flag, b0,
            qbase, kbase, vtbase);
        flash10<false, false><<<dim3(64, 1, nbc), 256, 0, stream>>>(
            b0, qbase, kbase, vtbase, flag, d_out, nullptr, nullptr);
    }
}

// Round 2
// 267.775 us; speedup vs baseline: 1.2474x; 1.2474x over previous
//
#include <hip/hip_runtime.h>

typedef __attribute__((ext_vector_type(8))) short short8;
typedef __attribute__((ext_vector_type(4))) short short4_t;
typedef __attribute__((ext_vector_type(4))) float float4_t;
typedef __attribute__((ext_vector_type(16))) float float16_t;
typedef __attribute__((ext_vector_type(2))) int int2_t;

#define NTOK 4096
#define CDIM 256
#define BPB (NTOK * CDIM)
#define C1 0.0901684400555602f   /* log2(e) / sqrt(256) */

__device__ inline float bf2f(short s) {
    return __uint_as_float(((unsigned)(unsigned short)s) << 16);
}
__device__ inline short f2bf(float f) {
    unsigned u = __float_as_uint(f);
    return (short)((u + 0x7fffu + ((u >> 16) & 1u)) >> 16);
}
__device__ inline int cvtpk_bf16(float lo, float hi) {
    int d;
    asm("v_cvt_pk_bf16_f32 %0, %1, %2" : "=v"(d) : "v"(lo), "v"(hi));
    return d;
}
// direct global->LDS DMA, 16B per lane, dest must be lane-linear
__device__ inline void gl_lds16(const void* g, void* l) {
    __builtin_amdgcn_global_load_lds(
        (const __attribute__((address_space(1))) unsigned int*)g,
        (__attribute__((address_space(3))) unsigned int*)l, 16, 0, 0);
}

// ---------------------------------------------------------------------------
__global__ void sniff_dtype(const unsigned* __restrict__ x, int* __restrict__ flag) {
    __shared__ int cnt;
    if (threadIdx.x == 0) cnt = 0;
    __syncthreads();
    int local = 0;
    for (int i = threadIdx.x; i < 1024; i += 256) {
        unsigned e = (x[i] >> 7) & 0xffu;
        if (e >= 100u && e <= 140u) local++;
    }
    atomicAdd(&cnt, local);
    __syncthreads();
    if (threadIdx.x == 0) flag[0] = (cnt >= 512) ? 1 : 0;
}

// ---------------------------------------------------------------------------
// wprep: convert Wq|Wk|Wv to bf16 into workspace (once; 768 KB read).
// ---------------------------------------------------------------------------
__global__ __launch_bounds__(256) void wprep(
    const void* __restrict__ Wq, const void* __restrict__ Wk,
    const void* __restrict__ Wv, const int* __restrict__ flag,
    short* __restrict__ Wb)
{
    const int base = (blockIdx.x * 256 + threadIdx.x) * 8;   // [0, 196608)
    const int wsel = base >> 16, off = base & 65535;
    const void* W = (wsel == 0) ? Wq : (wsel == 1) ? Wk : Wv;
    short8 v;
    if (flag[0]) {
        v = *(const short8*)((const short*)W + off);
    } else {
        const float* f = (const float*)W + off;
        float4 a = *(const float4*)f;
        float4 c4 = *(const float4*)(f + 4);
        v[0]=f2bf(a.x);  v[1]=f2bf(a.y);  v[2]=f2bf(a.z);  v[3]=f2bf(a.w);
        v[4]=f2bf(c4.x); v[5]=f2bf(c4.y); v[6]=f2bf(c4.z); v[7]=f2bf(c4.w);
    }
    *(short8*)(Wb + base) = v;
}

// ---------------------------------------------------------------------------
// qkv6: one block = 64 tokens x ONE of {Q,K,V}.  Grid 768 -> 3 blocks/CU,
// 3 waves/SIMD hide the direct-global W-load latency.  X transposed through
// LDS (one barrier); W read straight from Wb (L1/L2 hot).
// Outputs:
//   Q plain [n][d]
//   K swizzled 32-row tiles: off = (n>>5)*8192 + (n&31)*256
//                                  + (((d>>3) ^ (n&31))*8) + (d&7)
//   V swizzled [d][key] tiles: off = (n>>5)*8192 + d*32
//                                  + ((((n&31)>>3) ^ (d&3))*8) + (n&7)
// Both tile images are exactly what flash11 DMA-copies linearly into LDS.
// ---------------------------------------------------------------------------
template <bool PIN>
__global__ __launch_bounds__(256, 3) void qkv6(
    const void* __restrict__ xv, const short* __restrict__ Wb,
    const void* __restrict__ bq, const void* __restrict__ bk,
    const void* __restrict__ bv,
    const int* __restrict__ flag, int b0,
    short* __restrict__ qbase, short* __restrict__ kbase,
    short* __restrict__ vtbase)
{
    int nt, bl, wsel;
    if (PIN) {
        const int bid = blockIdx.x;          // 768
        wsel = bid >> 8;                      // 0..2
        const int rem = bid & 255;
        bl = rem & 3; nt = rem >> 2;
    } else { nt = blockIdx.x; wsel = blockIdx.y; bl = blockIdx.z; }
    const int b = b0 + bl;
    const int n0 = nt * 64;
    const int tid = threadIdx.x;
    const int w = tid >> 6, lane = tid & 63, l15 = lane & 15, qd = lane >> 4;
    const int isbf = flag[0];

    __shared__ short xt[64 * 264];     // 33792 B (only LDS use)

    // ---- stage X tile transposed: thread owns channel c = tid ----
    {
        const size_t xb = (size_t)b * CDIM * NTOK + (size_t)tid * NTOK + n0;
        if (isbf) {
            const short* x = (const short*)xv;
            #pragma unroll
            for (int i = 0; i < 8; ++i) {
                short8 v = *(const short8*)(x + xb + i * 8);
                #pragma unroll
                for (int j = 0; j < 8; ++j) xt[(i * 8 + j) * 264 + tid] = v[j];
            }
        } else {
            const float* x = (const float*)xv;
            #pragma unroll
            for (int i = 0; i < 16; ++i) {
                float4 v = *(const float4*)(x + xb + i * 4);
                xt[(i * 4 + 0) * 264 + tid] = f2bf(v.x);
                xt[(i * 4 + 1) * 264 + tid] = f2bf(v.y);
                xt[(i * 4 + 2) * 264 + tid] = f2bf(v.z);
                xt[(i * 4 + 3) * 264 + tid] = f2bf(v.w);
            }
        }
    }
    __syncthreads();   // the only barrier

    short8 af[8];
    #pragma unroll
    for (int s = 0; s < 8; ++s)
        af[s] = *(const short8*)&xt[(16 * w + l15) * 264 + s * 32 + qd * 8];

    const short* W = Wb + wsel * 65536;
    const void* bp = (wsel == 0) ? bq : (wsel == 1) ? bk : bv;
    short* qdst  = qbase  + (size_t)bl * BPB;
    short* kdst  = kbase  + (size_t)bl * BPB;
    short* vtdst = vtbase + (size_t)bl * BPB;

    #pragma unroll 2
    for (int dg = 0; dg < 16; ++dg) {
        const int d = dg * 16 + l15;
        const short* wr = W + (size_t)d * 256 + qd * 8;
        short8 wv[8];
        #pragma unroll
        for (int s = 0; s < 8; ++s) wv[s] = *(const short8*)(wr + s * 32);
        float4_t acc = {0.f, 0.f, 0.f, 0.f};
        #pragma unroll
        for (int s = 0; s < 8; ++s)
            acc = __builtin_amdgcn_mfma_f32_16x16x32_bf16(af[s], wv[s], acc, 0, 0, 0);
        const float bias = isbf ? bf2f(((const short*)bp)[d])
                                : ((const float*)bp)[d];
        if (wsel == 0) {
            #pragma unroll
            for (int r = 0; r < 4; ++r) {
                const int n = n0 + 16 * w + 4 * qd + r;
                qdst[(size_t)n * 256 + d] = f2bf(acc[r] + bias);
            }
        } else if (wsel == 1) {
            #pragma unroll
            for (int r = 0; r < 4; ++r) {
                const int n = n0 + 16 * w + 4 * qd + r;
                const int rl = n & 31;
                kdst[((size_t)(n >> 5)) * 8192 + rl * 256
                     + (((d >> 3) ^ rl) * 8) + (d & 7)] = f2bf(acc[r] + bias);
            }
        } else {
            short4_t pk;
            #pragma unroll
            for (int r = 0; r < 4; ++r) pk[r] = f2bf(acc[r] + bias);
            const int n = n0 + 16 * w + 4 * qd;          // 4-aligned
            const int kl = n & 31;
            *(short4_t*)(vtdst + ((size_t)(n >> 5)) * 8192 + d * 32
                         + (((kl >> 3) ^ (d & 3)) * 8) + (kl & 7)) = pk;
        }
    }
}

// ---------------------------------------------------------------------------
// flash11: QBLK=64, KVBLK=32.  All 4 waves compute S (wh = qrow half, wi
// duplicates); wi splits PV d-range.  P stays IN REGISTERS via
// cvt_pk_bf16 + permlane32_swap (no pbuf).  K,V double-buffered in LDS via
// global_load_lds from pre-swizzled tiles; DMA for kt+1 issued at TOP of
// iter kt (S+exp+PV covers latency); ONE barrier/iter.  LDS 66 KB ->
// 2 blocks/CU at grid 512 (SPLIT: halves of key range; combine() reduces).
// ---------------------------------------------------------------------------
template <bool PIN, bool SPLIT>
__global__ __launch_bounds__(256, 2) void flash11(
    int b0, const short* __restrict__ qb, const short* __restrict__ kb,
    const short* __restrict__ vtb, const int* __restrict__ flag,
    void* __restrict__ outv, float* __restrict__ pO, float* __restrict__ pl)
{
    int qt, bl, half;
    if (SPLIT) {
        const int bid = blockIdx.x;          // 512; bid&7 -> XCD owns (bl,half)
        bl = (bid >> 1) & 3; half = bid & 1; qt = bid >> 3;
    } else if (PIN) {
        bl = blockIdx.x & 3; qt = blockIdx.x >> 2; half = 0;
    } else { qt = blockIdx.x; bl = blockIdx.z; half = 0; }

    const int b = b0 + bl;
    const int q0 = qt * 64;
    const int tid = threadIdx.x;
    const int w = tid >> 6, lane = tid & 63, l31 = lane & 31, h = lane >> 5;
    const int wi = w & 1, wh = w >> 1;

    __shared__ __align__(16) char smem[67584];
    short* kbufA = (short*)smem;               // 2 x 16 KB
    short* vbufA = (short*)(smem + 32768);     // 2 x 16 KB

    const short* Q  = qb  + (size_t)bl * BPB;
    const char*  Kc = (const char*)(kb  + (size_t)bl * BPB);
    const char*  Vc = (const char*)(vtb + (size_t)bl * BPB);

    // Q B-frags: lane l31 -> qrow q0+32wh+l31, k = h*8 + j
    short8 qf[16];
    {
        const short* qrow = Q + (size_t)(q0 + 32 * wh + l31) * 256 + h * 8;
        #pragma unroll
        for (int s = 0; s < 16; ++s)
            qf[s] = *(const short8*)(qrow + s * 16);
    }

    float16_t oacc[4];
    #pragma unroll
    for (int dt = 0; dt < 4; ++dt)
        #pragma unroll
        for (int r = 0; r < 16; ++r) oacc[dt][r] = 0.f;
    float lloc = 0.f;

    const int KT0 = SPLIT ? half * 64 : 0;
    const int KT1 = KT0 + (SPLIT ? 64 : 128);

    // ---- prologue: stage tile KT0 into buffer 0 ----
    {
        const char* ks = Kc + ((size_t)KT0 << 14);
        const char* vs = Vc + ((size_t)KT0 << 14);
        char* kd = smem + tid * 16;
        char* vd = smem + 32768 + tid * 16;
        #pragma unroll
        for (int u = 0; u < 4; ++u) {
            gl_lds16(ks + u * 4096 + tid * 16, kd + u * 4096);
            gl_lds16(vs + u * 4096 + tid * 16, vd + u * 4096);
        }
    }
    __syncthreads();

    #pragma unroll 1
    for (int kt = KT0; kt < KT1; ++kt) {
        short* kcur = kbufA + (kt & 1) * 8192;
        short* vcur = vbufA + (kt & 1) * 8192;

        // ---- issue DMA for tile kt+1 (in flight through whole iter) ----
        if (kt + 1 < KT1) {
            const int alt = (kt + 1) & 1;
            const char* ks = Kc + ((size_t)(kt + 1) << 14);
            const char* vs = Vc + ((size_t)(kt + 1) << 14);
            char* kd = smem + alt * 16384 + tid * 16;
            char* vd = smem + 32768 + alt * 16384 + tid * 16;
            #pragma unroll
            for (int u = 0; u < 4; ++u) {
                gl_lds16(ks + u * 4096 + tid * 16, kd + u * 4096);
                gl_lds16(vs + u * 4096 + tid * 16, vd + u * 4096);
            }
        }

        // ---- S(kt): 32 keys x 32 qrows, k=256 -> 16 MFMAs, 2 chains ----
        float16_t se, so;
        #pragma unroll
        for (int r = 0; r < 16; ++r) { se[r] = 0.f; so[r] = 0.f; }
        #pragma unroll
        for (int j = 0; j < 8; ++j) {
            short8 ka = *(const short8*)
                &kcur[l31 * 256 + (((4 * j + h) ^ l31) * 8)];
            se = __builtin_amdgcn_mfma_f32_32x32x16_bf16(ka, qf[2 * j], se, 0, 0, 0);
            short8 kb2 = *(const short8*)
                &kcur[l31 * 256 + (((4 * j + 2 + h) ^ l31) * 8)];
            so = __builtin_amdgcn_mfma_f32_32x32x16_bf16(kb2, qf[2 * j + 1], so, 0, 0, 0);
        }

        // ---- P = exp2(C1*S), l accumulate ----
        float pf[16];
        #pragma unroll
        for (int r = 0; r < 16; ++r) {
            pf[r] = exp2f((se[r] + so[r]) * C1);
            lloc += pf[r];
        }

        // ---- in-register P -> A-frag repack (cvt_pk + permlane32_swap) ----
        // S gives lane(l31,h): P[key=(r&3)+8(r>>2)+4h][qrow=l31].
        // A-frag needs lane(l31,h): P[qrow=l31][keys s2*16+h*8+j].
        short8 pa[2];
        #pragma unroll
        for (int s2 = 0; s2 < 2; ++s2) {
            const int bse = s2 * 8;
            int x  = cvtpk_bf16(pf[bse + 0], pf[bse + 1]);
            int y  = cvtpk_bf16(pf[bse + 4], pf[bse + 5]);
            int z  = cvtpk_bf16(pf[bse + 2], pf[bse + 3]);
            int u2 = cvtpk_bf16(pf[bse + 6], pf[bse + 7]);
            int2_t r1 = __builtin_amdgcn_permlane32_swap(x, y, false, false);
            int2_t r2 = __builtin_amdgcn_permlane32_swap(z, u2, false, false);
            union { int i[4]; short8 s8; } uu;
            uu.i[0] = r1[0]; uu.i[1] = r2[0]; uu.i[2] = r1[1]; uu.i[3] = r2[1];
            pa[s2] = uu.s8;
        }

        // ---- PV(kt): qrows 32wh x dims 128wi..+128, 8 MFMAs ----
        #pragma unroll
        for (int dt = 0; dt < 4; ++dt) {
            const int d = 128 * wi + 32 * dt + l31;
            #pragma unroll
            for (int s2 = 0; s2 < 2; ++s2) {
                short8 vf = *(const short8*)
                    &vcur[d * 32 + (((2 * s2 + h) ^ (d & 3)) * 8)];
                oacc[dt] = __builtin_amdgcn_mfma_f32_32x32x16_bf16(pa[s2], vf, oacc[dt], 0, 0, 0);
            }
        }

        __syncthreads();   // ONE barrier: drains DMA(kt+1), fences buf reuse
    }

    // ---- l per qrow (wi waves duplicate S -> only wi==0 writes) ----
    float* lbuf = (float*)(smem + 66560);   // 64 floats
    {
        float v2 = lloc + __shfl_xor(lloc, 32, 64);
        if (h == 0 && wi == 0) lbuf[32 * wh + l31] = v2;
    }

    if (SPLIT) {
        const size_t pidx = (size_t)(bl * 64 + qt) * 2 + half;
        float* po = pO + pidx * 16384;
        #pragma unroll
        for (int dt = 0; dt < 4; ++dt) {
            const int dim = 128 * wi + 32 * dt + l31;
            #pragma unroll
            for (int r = 0; r < 16; ++r) {
                const int qrow = 32 * wh + (r & 3) + 8 * (r >> 2) + 4 * h;
                po[qrow * 256 + dim] = oacc[dt][r];
            }
        }
        __syncthreads();
        if (tid < 64) pl[pidx * 64 + tid] = lbuf[tid];
    } else {
        float* obuf = (float*)smem;               // 64 x 260 fp32 (overlays bufs)
        #pragma unroll
        for (int dt = 0; dt < 4; ++dt) {
            const int dim = 128 * wi + 32 * dt + l31;
            #pragma unroll
            for (int r = 0; r < 16; ++r) {
                const int qrow = 32 * wh + (r & 3) + 8 * (r >> 2) + 4 * h;
                obuf[qrow * 260 + dim] = oacc[dt][r];
            }
        }
        __syncthreads();
        {
            const int row = tid >> 2, q4 = (tid & 3) * 64;
            const float inv = 1.0f / lbuf[row];
            const float* src = obuf + row * 260 + q4;
            const size_t o = (size_t)(b * NTOK + q0 + row) * 256 + q4;
            if (flag[0]) {
                short* op = (short*)outv;
                #pragma unroll
                for (int g = 0; g < 4; ++g) {
                    float4 a  = *(const float4*)(src + g * 8);
                    float4 c4 = *(const float4*)(src + g * 8 + 4);
                    short8 pk;
                    pk[0]=f2bf(a.x*inv);  pk[1]=f2bf(a.y*inv);
                    pk[2]=f2bf(a.z*inv);  pk[3]=f2bf(a.w*inv);
                    pk[4]=f2bf(c4.x*inv); pk[5]=f2bf(c4.y*inv);
                    pk[6]=f2bf(c4.z*inv); pk[7]=f2bf(c4.w*inv);
                    *(short8*)(op + o + g * 8) = pk;
                }
            } else {
                float* op = (float*)outv;
                #pragma unroll
                for (int g = 0; g < 16; ++g) {
                    float4 a = *(const float4*)(src + g * 4);
                    a.x *= inv; a.y *= inv; a.z *= inv; a.w *= inv;
                    *(float4*)(op + o + g * 4) = a;
                }
            }
        }
    }
}

// ---------------------------------------------------------------------------
// combine: out[n][d] = (Oa+Ob) / (la+lb), cast per flag.  Grid 256 (tiles).
// ---------------------------------------------------------------------------
__global__ __launch_bounds__(256) void combine(
    const float* __restrict__ pO, const float* __restrict__ pl,
    const int* __restrict__ flag, void* __restrict__ outv)
{
    const int tile = blockIdx.x, tid = threadIdx.x;
    const int row = tid >> 2, seg = (tid & 3) * 64;
    const float* A = pO + (size_t)tile * 32768 + row * 256 + seg;
    const float* B = A + 16384;
    const float inv = 1.0f / (pl[tile * 128 + row] + pl[tile * 128 + 64 + row]);
    const size_t o = ((size_t)tile * 64 + row) * 256 + seg;
    if (flag[0]) {
        short* op = (short*)outv;
        #pragma unroll
        for (int g = 0; g < 8; ++g) {
            float4 a  = *(const float4*)(A + g * 8);
            float4 a2 = *(const float4*)(A + g * 8 + 4);
            float4 c  = *(const float4*)(B + g * 8);
            float4 c2 = *(const float4*)(B + g * 8 + 4);
            short8 pk;
            pk[0]=f2bf((a.x+c.x)*inv);   pk[1]=f2bf((a.y+c.y)*inv);
            pk[2]=f2bf((a.z+c.z)*inv);   pk[3]=f2bf((a.w+c.w)*inv);
            pk[4]=f2bf((a2.x+c2.x)*inv); pk[5]=f2bf((a2.y+c2.y)*inv);
            pk[6]=f2bf((a2.z+c2.z)*inv); pk[7]=f2bf((a2.w+c2.w)*inv);
            *(short8*)(op + o + g * 8) = pk;
        }
    } else {
        float* op = (float*)outv;
        #pragma unroll
        for (int g = 0; g < 16; ++g) {
            float4 a = *(const float4*)(A + g * 4);
            float4 c = *(const float4*)(B + g * 4);
            a.x = (a.x + c.x) * inv; a.y = (a.y + c.y) * inv;
            a.z = (a.z + c.z) * inv; a.w = (a.w + c.w) * inv;
            *(float4*)(op + o + g * 4) = a;
        }
    }
}

extern "C" void kernel_launch(void* const* d_in, const int* in_sizes, int n_in,
                              void* d_out, int out_size, void* d_ws, size_t ws_size,
                              hipStream_t stream)
{
    const size_t HDR = 256;
    const size_t WBB = 393216;                     // 3 x 256 x 256 bf16
    const size_t TB  = (size_t)BPB * 2;            // 2 MB per batch per tensor
    const size_t OFF_K = HDR + WBB;
    const size_t need_prim  = OFF_K + 12 * TB;               // + K|VT|Q (24 MB)
    const size_t need_split = need_prim + 33554432 + 131072; // + partials

    int*   flag = (int*)d_ws;
    short* Wb   = (short*)((char*)d_ws + HDR);

    sniff_dtype<<<1, 256, 0, stream>>>((const unsigned*)d_in[0], flag);
    wprep<<<96, 256, 0, stream>>>(d_in[1], d_in[3], d_in[5], flag, Wb);

    if (ws_size >= need_prim) {
        short* kbase  = (short*)((char*)d_ws + OFF_K);
        short* vtbase = kbase  + 4 * (size_t)BPB;
        short* qbase  = vtbase + 4 * (size_t)BPB;
        qkv6<true><<<dim3(768, 1, 1), 256, 0, stream>>>(
            d_in[0], Wb, d_in[2], d_in[4], d_in[6], flag, 0,
            qbase, kbase, vtbase);
        if (ws_size >= need_split) {
            float* pO = (float*)((char*)d_ws + need_prim);
            float* pl = (float*)((char*)d_ws + need_prim + 33554432);
            flash11<true, true><<<dim3(512, 1, 1), 256, 0, stream>>>(
                0, qbase, kbase, vtbase, flag, d_out, pO, pl);
            combine<<<dim3(256, 1, 1), 256, 0, stream>>>(pO, pl, flag, d_out);
        } else {
            flash11<true, false><<<dim3(256, 1, 1), 256, 0, stream>>>(
                0, qbase, kbase, vtbase, flag, d_out, nullptr, nullptr);
        }
        return;
    }

    // fallback: batch-chunked (K|VT|Q per chunk = 6 MB/batch)
    int nb = 4;
    while (nb > 1 && ws_size < OFF_K + (size_t)nb * 3 * TB) nb--;
    short* kbase  = (short*)((char*)d_ws + OFF_K);
    short* vtbase = kbase + (size_t)nb * BPB;
    short* qbase  = vtbase + (size_t)nb * BPB;

    for (int b0 = 0; b0 < 4; b0 += nb) {
        const int nbc = (4 - b0) < nb ? (4 - b0) : nb;
        qkv6<false><<<dim3(64, 3, nbc), 256, 0, stream>>>(
            d_in[0], Wb, d_in[2], d_in[4], d_in[6], flag, b0,
            qbase, kbase, vtbase);
        flash11<false, false><<<dim3(64, 1, nbc), 256, 0, stream>>>(
            b0, qbase, kbase, vtbase, flag, d_out, nullptr, nullptr);
    }
}